// Round 1
// baseline (553.408 us; speedup 1.0000x reference)
//
#include <hip/hip_runtime.h>
#include <math.h>

#define BSZ 16
#define SEQ 2048
#define DKD 64
#define QT 64
#define KT 64
#define NTH 256

// Flash-style causal attention with relative-position (skew-trick) bias.
// bias[r, j] = Q[r] . Krelpos[:, (S-1)-(r-j)]  for j <= r  (masked otherwise)
//
// Block = 256 threads = (ty in [0,16)) x (tx in [0,16)); each thread owns a
// 4x4 score tile (queries qrow..qrow+3, keys kcol..kcol+3) and a 4x4 output
// tile (queries qrow..qrow+3, dims kcol..kcol+3).
__launch_bounds__(NTH, 2)
__global__ void attn_fused(const float* __restrict__ Q,
                           const float* __restrict__ K,
                           const float* __restrict__ V,
                           const float* __restrict__ P,   // [DKD][SEQ]
                           float* __restrict__ O) {
  // LDS budget: 16384 + 16640 + 16384 + 32512 = 81920 B = 80 KB -> 2 blocks/CU
  __shared__ __align__(16) float QsT[DKD][QT];        // Q tile, transposed [d][q]
  __shared__ __align__(16) float Ks[KT][DKD + 1];     // K tile [k][d]; reused as probs [q][k]
  __shared__ __align__(16) float Vs[KT][DKD];         // V tile [k][d]
  __shared__ __align__(16) float Pslab[DKD][127];     // Krelpos window [d][c]

  const int tid = threadIdx.x;
  const int tx = tid & 15;
  const int ty = tid >> 4;
  const int bid = blockIdx.x;
  const int b = bid & (BSZ - 1);
  const int qt = (SEQ / QT - 1) - (bid >> 4);   // heavy query-tiles launch first
  const int r0 = qt * QT;

  const int qrow = ty * 4;
  const int kcol = tx * 4;
  const int pb = 60 + 4 * (tx - ty);            // Pslab base offset (range [0,120])
  const float tfac = 0.125f * 1.44269504088896f; // (1/sqrt(64)) * log2(e)

  // ---- stage Q tile (transposed into LDS; staging conflicts are once-only) ----
  const float* Qb = Q + ((size_t)b * SEQ + r0) * DKD;
  for (int k = 0; k < 4; ++k) {
    int i4 = tid + k * NTH;          // float4 index within 64x64 tile
    int r = i4 >> 4;
    int c = (i4 & 15) << 2;
    float4 v = *(const float4*)(Qb + r * DKD + c);
    QsT[c + 0][r] = v.x; QsT[c + 1][r] = v.y;
    QsT[c + 2][r] = v.z; QsT[c + 3][r] = v.w;
  }

  float acc[4][4] = {};
  float mrow[4] = {-INFINITY, -INFINITY, -INFINITY, -INFINITY};
  float lrow[4] = {};

  for (int kt = 0; kt <= qt; ++kt) {
    const int j0 = kt * KT;
    __syncthreads();   // previous iteration's AV reads done before overwrite

    // ---- stage K, V tiles ----
    const float* Kb = K + ((size_t)b * SEQ + j0) * DKD;
    const float* Vb = V + ((size_t)b * SEQ + j0) * DKD;
    for (int k = 0; k < 4; ++k) {
      int i4 = tid + k * NTH;
      int r = i4 >> 4;
      int c = (i4 & 15) << 2;
      float4 kv = *(const float4*)(Kb + r * DKD + c);
      Ks[r][c + 0] = kv.x; Ks[r][c + 1] = kv.y;
      Ks[r][c + 2] = kv.z; Ks[r][c + 3] = kv.w;
      float4 vv = *(const float4*)(Vb + r * DKD + c);
      *(float4*)(&Vs[r][c]) = vv;
    }
    // ---- stage Krelpos slab: global columns cstart .. cstart+126 ----
    const int cstart = (SEQ - 1) - r0 + j0 - 63;  // >= 0 always
    for (int i = tid; i < DKD * 128; i += NTH) {
      int d = i >> 7;
      int c = i & 127;
      if (c < 127) {
        int cg = cstart + c;
        float v = 0.0f;
        if (cg < SEQ) v = P[(size_t)d * SEQ + cg];  // cg >= 0 guaranteed
        Pslab[d][c] = v;
      }
    }
    __syncthreads();

    // ---- scores: QK + skewed bias, 4x4 per thread ----
    float s[4][4] = {};
    #pragma unroll 4
    for (int d = 0; d < DKD; ++d) {
      float qv[4], kv[4], pv[7];
      #pragma unroll
      for (int i = 0; i < 4; ++i) qv[i] = QsT[d][qrow + i];
      #pragma unroll
      for (int i = 0; i < 4; ++i) kv[i] = Ks[kcol + i][d];
      #pragma unroll
      for (int t = 0; t < 7; ++t) pv[t] = Pslab[d][pb + t];
      #pragma unroll
      for (int qi = 0; qi < 4; ++qi)
        #pragma unroll
        for (int kj = 0; kj < 4; ++kj)
          s[qi][kj] += qv[qi] * (kv[kj] + pv[3 + kj - qi]);
    }

    // ---- online softmax (exp2 domain), row reductions across 16 tx lanes ----
    const bool diag = (kt == qt);
    float p[4][4];
    #pragma unroll
    for (int qi = 0; qi < 4; ++qi) {
      float t0[4];
      #pragma unroll
      for (int kj = 0; kj < 4; ++kj) {
        float t = s[qi][kj] * tfac;
        if (diag && (kcol + kj > qrow + qi)) t = -INFINITY;
        t0[kj] = t;
      }
      float rm = fmaxf(fmaxf(t0[0], t0[1]), fmaxf(t0[2], t0[3]));
      #pragma unroll
      for (int m = 1; m < 16; m <<= 1) rm = fmaxf(rm, __shfl_xor(rm, m, 16));
      float mn = fmaxf(mrow[qi], rm);
      float alpha = exp2f(mrow[qi] - mn);   // -inf - finite -> 0, no NaN
      mrow[qi] = mn;
      float rs = 0.0f;
      #pragma unroll
      for (int kj = 0; kj < 4; ++kj) {
        float e = exp2f(t0[kj] - mn);
        p[qi][kj] = e;
        rs += e;
      }
      #pragma unroll
      for (int m = 1; m < 16; m <<= 1) rs += __shfl_xor(rs, m, 16);
      lrow[qi] = lrow[qi] * alpha + rs;
      #pragma unroll
      for (int dj = 0; dj < 4; ++dj) acc[qi][dj] *= alpha;
    }

    // ---- probs -> LDS (reuse Ks region; it is dead now) ----
    __syncthreads();
    #pragma unroll
    for (int qi = 0; qi < 4; ++qi)
      #pragma unroll
      for (int kj = 0; kj < 4; ++kj)
        Ks[qrow + qi][kcol + kj] = p[qi][kj];
    __syncthreads();

    // ---- AV accumulate: 4 queries x 4 output dims per thread ----
    for (int kk = 0; kk < KT; ++kk) {
      float pr[4], vv[4];
      #pragma unroll
      for (int qi = 0; qi < 4; ++qi) pr[qi] = Ks[qrow + qi][kk];
      #pragma unroll
      for (int dj = 0; dj < 4; ++dj) vv[dj] = Vs[kk][kcol + dj];
      #pragma unroll
      for (int qi = 0; qi < 4; ++qi)
        #pragma unroll
        for (int dj = 0; dj < 4; ++dj)
          acc[qi][dj] += pr[qi] * vv[dj];
    }
  }

  // ---- epilogue: normalize and store ----
  float* Ob = O + ((size_t)b * SEQ + r0) * DKD;
  #pragma unroll
  for (int qi = 0; qi < 4; ++qi) {
    float rl = 1.0f / lrow[qi];
    float4 o;
    o.x = acc[qi][0] * rl;
    o.y = acc[qi][1] * rl;
    o.z = acc[qi][2] * rl;
    o.w = acc[qi][3] * rl;
    *(float4*)(Ob + (qrow + qi) * DKD + kcol) = o;
  }
}

extern "C" void kernel_launch(void* const* d_in, const int* in_sizes, int n_in,
                              void* d_out, int out_size, void* d_ws, size_t ws_size,
                              hipStream_t stream) {
  const float* Q = (const float*)d_in[0];
  const float* K = (const float*)d_in[1];
  const float* V = (const float*)d_in[2];
  const float* P = (const float*)d_in[3];  // Krelpos [DKD][SEQ]
  float* O = (float*)d_out;

  dim3 grid(BSZ * (SEQ / QT));  // 512 blocks; qt reversed inside kernel
  dim3 block(NTH);
  hipLaunchKernelGGL(attn_fused, grid, block, 0, stream, Q, K, V, P, O);
}

// Round 2
// 179.914 us; speedup vs baseline: 3.0760x; 3.0760x over previous
//
#include <hip/hip_runtime.h>
#include <math.h>

#define BSZ 16
#define SEQ 2048
#define DKD 64
#define NTH 256

typedef __attribute__((ext_vector_type(8))) short bf16x8;
typedef __attribute__((ext_vector_type(4))) float f32x4;

__device__ __forceinline__ short f2bf(float x) {
  union { float f; unsigned u; } c; c.f = x;
  unsigned r = c.u + 0x7fffu + ((c.u >> 16) & 1u);
  return (short)(r >> 16);
}

// bijective row swizzle on [0,64): breaks bank conflicts of transposed staging
__device__ __forceinline__ int swz(int x) { return x ^ ((x >> 3) & 7); }

__launch_bounds__(NTH, 2)
__global__ void attn_mfma(const float* __restrict__ Q,
                          const float* __restrict__ K,
                          const float* __restrict__ V,
                          const float* __restrict__ P,   // Krelpos [DKD][SEQ]
                          float* __restrict__ O) {
  // LDS: 9216*3 + 21504 + 18432 = 67584 B -> 2 blocks/CU
  __shared__ __align__(16) short Ks[64][72];     // K tile [key][dim], bf16
  __shared__ __align__(16) short VsT[64][72];    // V^T [swz(dim)][key], bf16
  __shared__ __align__(16) short PsT[128][72];   // Krelpos [64*(blk&1)+swz(c&63)][dim]
  __shared__ __align__(16) float Tb[4][16][84];  // per-wave bias strip, local cols 0..79
  __shared__ __align__(16) short Pp[64][72];     // probs [row][key], bf16 (wave-private rows)

  const int tid = threadIdx.x;
  const int lane = tid & 63;
  const int wave = tid >> 6;
  const int l16 = lane & 15;
  const int quad = lane >> 4;
  const int b = blockIdx.x & (BSZ - 1);
  const int qt = (SEQ / 64 - 1) - (blockIdx.x >> 4);  // heavy tiles first
  const int r0 = qt * 64;
  const float tfac = 0.125f * 1.4426950408889634f;    // (1/sqrt(64)) * log2(e)

  // ---- persistent Q A-fragments: A[m=l16][k=quad*8+j], two 32-wide k-chunks ----
  bf16x8 aq[2];
  {
    const float* Qr = Q + ((size_t)(b * SEQ + r0 + wave * 16 + l16)) * DKD + quad * 8;
    #pragma unroll
    for (int ks = 0; ks < 2; ++ks) {
      float4 x = *(const float4*)(Qr + ks * 32);
      float4 y = *(const float4*)(Qr + ks * 32 + 4);
      bf16x8 t;
      t[0] = f2bf(x.x); t[1] = f2bf(x.y); t[2] = f2bf(x.z); t[3] = f2bf(x.w);
      t[4] = f2bf(y.x); t[5] = f2bf(y.y); t[6] = f2bf(y.z); t[7] = f2bf(y.w);
      aq[ks] = t;
    }
  }

  f32x4 oacc[4];
  #pragma unroll
  for (int i = 0; i < 4; ++i)
    #pragma unroll
    for (int j = 0; j < 4; ++j) oacc[i][j] = 0.f;
  float mrow[4] = {-INFINITY, -INFINITY, -INFINITY, -INFINITY};
  float lrow[4] = {0.f, 0.f, 0.f, 0.f};

  const int Blo0 = 31 - qt;  // low 64-col block of the Krelpos window at kt=0

  // stage one 64-column block of Krelpos into its circular panel
  auto stagePanel = [&](int Bg) {
    int base = 64 * (Bg & 1);
    #pragma unroll
    for (int it = 0; it < 4; ++it) {
      int idx4 = tid + it * NTH;        // 0..1023 float4s
      int d = idx4 >> 4;
      int c4 = (idx4 & 15) << 2;
      float4 pv = {0.f, 0.f, 0.f, 0.f};
      if (Bg < 32) pv = *(const float4*)(P + (size_t)d * SEQ + Bg * 64 + c4);
      PsT[base + swz(c4 + 0)][d] = f2bf(pv.x);
      PsT[base + swz(c4 + 1)][d] = f2bf(pv.y);
      PsT[base + swz(c4 + 2)][d] = f2bf(pv.z);
      PsT[base + swz(c4 + 3)][d] = f2bf(pv.w);
    }
  };

  for (int kt = 0; kt <= qt; ++kt) {
    const int j0 = kt * 64;
    __syncthreads();  // all waves done reading previous tiles

    // ---- stage K (natural) and V (transposed, swizzled rows) ----
    const float* Kb = K + ((size_t)(b * SEQ + j0)) * DKD;
    const float* Vb = V + ((size_t)(b * SEQ + j0)) * DKD;
    #pragma unroll
    for (int it = 0; it < 4; ++it) {
      int i4 = tid + it * NTH;
      int r = i4 >> 4, c = (i4 & 15) << 2;
      float4 kv = *(const float4*)(Kb + r * DKD + c);
      ushort4 kp;
      kp.x = (unsigned short)f2bf(kv.x);
      kp.y = (unsigned short)f2bf(kv.y);
      kp.z = (unsigned short)f2bf(kv.z);
      kp.w = (unsigned short)f2bf(kv.w);
      *(ushort4*)&Ks[r][c] = kp;
      float4 vv = *(const float4*)(Vb + r * DKD + c);
      VsT[swz(c + 0)][r] = f2bf(vv.x);
      VsT[swz(c + 1)][r] = f2bf(vv.y);
      VsT[swz(c + 2)][r] = f2bf(vv.z);
      VsT[swz(c + 3)][r] = f2bf(vv.w);
    }
    if (kt == 0) stagePanel(Blo0);
    stagePanel(Blo0 + kt + 1);   // new high block (>=32 -> zeros)
    __syncthreads();

    // ---- QK scores: 16x16 tiles, B[k][n=l16] from Ks rows ----
    f32x4 sacc[4];
    #pragma unroll
    for (int i = 0; i < 4; ++i)
      #pragma unroll
      for (int j = 0; j < 4; ++j) sacc[i][j] = 0.f;
    #pragma unroll
    for (int ks = 0; ks < 2; ++ks)
      #pragma unroll
      for (int t = 0; t < 4; ++t) {
        bf16x8 bk = *(const bf16x8*)&Ks[t * 16 + l16][ks * 32 + quad * 8];
        sacc[t] = __builtin_amdgcn_mfma_f32_16x16x32_bf16(aq[ks], bk, sacc[t], 0, 0, 0);
      }

    // ---- bias: only the 5 column-tiles this wave's rows need ----
    f32x4 bacc[5];
    #pragma unroll
    for (int i = 0; i < 5; ++i)
      #pragma unroll
      for (int j = 0; j < 4; ++j) bacc[i][j] = 0.f;
    #pragma unroll
    for (int tt = 0; tt < 5; ++tt) {
      int c = (tt + 3 - wave) * 16 + l16;  // slab col 0..127
      int prow = 64 * ((Blo0 + kt + (c >> 6)) & 1) + swz(c & 63);
      #pragma unroll
      for (int ks = 0; ks < 2; ++ks) {
        bf16x8 bp = *(const bf16x8*)&PsT[prow][ks * 32 + quad * 8];
        bacc[tt] = __builtin_amdgcn_mfma_f32_16x16x32_bf16(aq[ks], bp, bacc[tt], 0, 0, 0);
      }
    }
    // write bias strip (wave-private)
    #pragma unroll
    for (int tt = 0; tt < 5; ++tt)
      #pragma unroll
      for (int r = 0; r < 4; ++r)
        Tb[wave][quad * 4 + r][tt * 16 + l16] = bacc[tt][r];

    // ---- gather skewed bias, scale, mask; online softmax ----
    const bool diag = (kt == qt);
    float p[4][4];
    #pragma unroll
    for (int r = 0; r < 4; ++r) {
      const int rs = quad * 4 + r;  // row within wave strip
      float sv[4];
      #pragma unroll
      for (int t = 0; t < 4; ++t) {
        int jl = t * 16 + l16;
        float sc = sacc[t][r] + Tb[wave][rs][15 + jl - rs];
        sc *= tfac;
        if (diag && jl > wave * 16 + rs) sc = -INFINITY;
        sv[t] = sc;
      }
      float rm = fmaxf(fmaxf(sv[0], sv[1]), fmaxf(sv[2], sv[3]));
      #pragma unroll
      for (int m = 1; m < 16; m <<= 1) rm = fmaxf(rm, __shfl_xor(rm, m, 16));
      float mn = fmaxf(mrow[r], rm);
      float alpha = exp2f(mrow[r] - mn);
      mrow[r] = mn;
      float ls = 0.f;
      #pragma unroll
      for (int t = 0; t < 4; ++t) {
        float e = exp2f(sv[t] - mn);
        p[t][r] = e;
        ls += e;
      }
      #pragma unroll
      for (int m = 1; m < 16; m <<= 1) ls += __shfl_xor(ls, m, 16);
      lrow[r] = lrow[r] * alpha + ls;
      #pragma unroll
      for (int dt = 0; dt < 4; ++dt) oacc[dt][r] *= alpha;
    }

    // ---- probs -> LDS (wave-private rows), then PV MFMA ----
    #pragma unroll
    for (int t = 0; t < 4; ++t)
      #pragma unroll
      for (int r = 0; r < 4; ++r)
        Pp[wave * 16 + quad * 4 + r][t * 16 + l16] = f2bf(p[t][r]);

    #pragma unroll
    for (int ks = 0; ks < 2; ++ks) {
      bf16x8 ap = *(const bf16x8*)&Pp[wave * 16 + l16][ks * 32 + quad * 8];
      #pragma unroll
      for (int dt = 0; dt < 4; ++dt) {
        bf16x8 bv = *(const bf16x8*)&VsT[swz(dt * 16 + l16)][ks * 32 + quad * 8];
        oacc[dt] = __builtin_amdgcn_mfma_f32_16x16x32_bf16(ap, bv, oacc[dt], 0, 0, 0);
      }
    }
  }

  // ---- epilogue ----
  float* Ob = O + ((size_t)(b * SEQ + r0)) * DKD;
  #pragma unroll
  for (int r = 0; r < 4; ++r) {
    float rl = 1.f / lrow[r];
    int row = wave * 16 + quad * 4 + r;
    #pragma unroll
    for (int dt = 0; dt < 4; ++dt)
      Ob[(size_t)row * DKD + dt * 16 + l16] = oacc[dt][r] * rl;
  }
}

extern "C" void kernel_launch(void* const* d_in, const int* in_sizes, int n_in,
                              void* d_out, int out_size, void* d_ws, size_t ws_size,
                              hipStream_t stream) {
  const float* Q = (const float*)d_in[0];
  const float* K = (const float*)d_in[1];
  const float* V = (const float*)d_in[2];
  const float* P = (const float*)d_in[3];
  float* O = (float*)d_out;

  dim3 grid(BSZ * (SEQ / 64));  // 512 blocks
  dim3 block(NTH);
  hipLaunchKernelGGL(attn_mfma, grid, block, 0, stream, Q, K, V, P, O);
}

// Round 3
// 163.980 us; speedup vs baseline: 3.3748x; 1.0972x over previous
//
#include <hip/hip_runtime.h>
#include <math.h>

#define BSZ 16
#define SEQ 2048
#define DKD 64
#define NTH 256

typedef __attribute__((ext_vector_type(8))) short bf16x8;
typedef __attribute__((ext_vector_type(8))) short short8;
typedef __attribute__((ext_vector_type(4))) float f32x4;

__device__ __forceinline__ short f2bf(float x) {
  union { float f; unsigned u; } c; c.f = x;
  unsigned r = c.u + 0x7fffu + ((c.u >> 16) & 1u);
  return (short)(r >> 16);
}

// async 16B/lane global->LDS DMA; ldst must be wave-uniform, lane i lands at ldst + i*16
#define GLD16(gsrc, ldst)                                                                  \
  __builtin_amdgcn_global_load_lds((const __attribute__((address_space(1))) void*)(gsrc), \
                                   (__attribute__((address_space(3))) void*)(ldst), 16, 0, 0)

// XOR chunk swizzle: logical (row, 16B-chunk c8) -> physical chunk index
#define CH(row, c8) (((row) << 3) + ((c8) ^ ((row) & 7)))

// ---------------- pre-kernel: bf16 convert K, transpose+convert V and P ----------------
// ws layout: K_bf [16][2048][64]  @ 0        (4,194,304 B)
//            VT_bf[16][64][2048]  @ 4194304  (4,194,304 B)
//            PT_bf[2112][64]      @ 8388608  (270,336 B; rows 2048..2111 zero)
__launch_bounds__(NTH)
__global__ void pre_convert(const float* __restrict__ K, const float* __restrict__ V,
                            const float* __restrict__ P, short* __restrict__ Kbf,
                            short* __restrict__ VTbf, short* __restrict__ PTbf) {
  __shared__ short T[64 * 65];
  const int blk = blockIdx.x;
  const int tid = threadIdx.x;
  if (blk < 512) {
    const int b = blk >> 5, st = blk & 31;
    const float* Kb = K + ((size_t)(b * SEQ + st * 64)) * DKD;
    const float* Vb = V + ((size_t)(b * SEQ + st * 64)) * DKD;
    short* Ko = Kbf + ((size_t)(b * SEQ + st * 64)) * DKD;
    const int r = tid >> 2, c4 = (tid & 3) << 4;
    #pragma unroll
    for (int j4 = 0; j4 < 4; ++j4) {
      const int c = c4 + j4 * 4;
      float4 kv = *(const float4*)(Kb + r * DKD + c);
      ushort4 kp;
      kp.x = (unsigned short)f2bf(kv.x); kp.y = (unsigned short)f2bf(kv.y);
      kp.z = (unsigned short)f2bf(kv.z); kp.w = (unsigned short)f2bf(kv.w);
      *(ushort4*)(Ko + r * DKD + c) = kp;
      float4 vv = *(const float4*)(Vb + r * DKD + c);
      T[(c + 0) * 65 + r] = f2bf(vv.x);
      T[(c + 1) * 65 + r] = f2bf(vv.y);
      T[(c + 2) * 65 + r] = f2bf(vv.z);
      T[(c + 3) * 65 + r] = f2bf(vv.w);
    }
    __syncthreads();
    const int d = tid >> 2, s4 = (tid & 3) << 4;
    short* Vo = VTbf + ((size_t)(b * DKD + d)) * SEQ + st * 64 + s4;
    short8 w0, w1;
    #pragma unroll
    for (int j = 0; j < 8; ++j) { w0[j] = T[d * 65 + s4 + j]; w1[j] = T[d * 65 + s4 + 8 + j]; }
    *(short8*)(Vo + 0) = w0;
    *(short8*)(Vo + 8) = w1;
  } else if (blk < 544) {
    const int c0 = (blk - 512) * 64;
    const int d = tid >> 2, cc4 = (tid & 3) << 4;
    #pragma unroll
    for (int j4 = 0; j4 < 4; ++j4) {
      const int c = cc4 + j4 * 4;
      float4 pv = *(const float4*)(P + (size_t)d * SEQ + c0 + c);
      T[(c + 0) * 65 + d] = f2bf(pv.x);
      T[(c + 1) * 65 + d] = f2bf(pv.y);
      T[(c + 2) * 65 + d] = f2bf(pv.z);
      T[(c + 3) * 65 + d] = f2bf(pv.w);
    }
    __syncthreads();
    const int c = tid >> 2, d4 = (tid & 3) << 4;
    short8 w0, w1;
    #pragma unroll
    for (int j = 0; j < 8; ++j) { w0[j] = T[c * 65 + d4 + j]; w1[j] = T[c * 65 + d4 + 8 + j]; }
    short* Po = PTbf + ((size_t)(c0 + c)) * DKD + d4;
    *(short8*)(Po + 0) = w0;
    *(short8*)(Po + 8) = w1;
  } else {
    // zero pad rows 2048..2111 of PT (read when the rel-pos window slides past col 2047)
    short8 z = {0, 0, 0, 0, 0, 0, 0, 0};
    short* Po = PTbf + (size_t)SEQ * DKD + tid * 16;
    *(short8*)(Po + 0) = z;
    *(short8*)(Po + 8) = z;
  }
}

// ---------------- main attention kernel ----------------
__launch_bounds__(NTH, 3)
__global__ void attn_mfma2(const float* __restrict__ Q,
                           const short* __restrict__ Kbf,
                           const short* __restrict__ VTbf,
                           const short* __restrict__ PTbf,
                           float* __restrict__ O) {
  // 8KB each (chunk-swizzled, unpadded -> DMA-compatible): total 40KB -> up to 4 blocks/CU
  __shared__ __align__(16) short Ks[64 * 64];       // K tile  [key][dim]
  __shared__ __align__(16) short VsT[64 * 64];      // V^T     [dim][key]
  __shared__ __align__(16) short PsT[2 * 64 * 64];  // relpos  [2 panels][col][dim]
  __shared__ __align__(16) short Pp[64 * 64];       // probs   [row][key] (wave-private rows)

  const int tid = threadIdx.x;
  const int lane = tid & 63;
  const int wave = tid >> 6;
  const int l16 = lane & 15;
  const int quad = lane >> 4;
  const int i = blockIdx.x;
  const int b = i & 15;
  const int h = i >> 4;
  // balanced pairing: CU c gets blocks c (qt 31..16) and c+256 (qt 0..15) -> ~33 iters each
  const int qt = (i < 256) ? (31 - h) : (h - 16);
  const int r0 = qt * 64;
  const float SC = 0.125f * 1.4426950408889634f;  // (1/sqrt(dk)) * log2(e), folded into Q

  // ---- persistent pre-scaled Q A-fragments ----
  bf16x8 aq[2];
  {
    const float* Qr = Q + ((size_t)(b * SEQ + r0 + wave * 16 + l16)) * DKD + quad * 8;
    #pragma unroll
    for (int ks = 0; ks < 2; ++ks) {
      float4 x = *(const float4*)(Qr + ks * 32);
      float4 y = *(const float4*)(Qr + ks * 32 + 4);
      bf16x8 t;
      t[0] = f2bf(x.x * SC); t[1] = f2bf(x.y * SC); t[2] = f2bf(x.z * SC); t[3] = f2bf(x.w * SC);
      t[4] = f2bf(y.x * SC); t[5] = f2bf(y.y * SC); t[6] = f2bf(y.z * SC); t[7] = f2bf(y.w * SC);
      aq[ks] = t;
    }
  }

  // ---- skew-gather lane tables: bias(rs, jl) lives at source lane quad*16 + ((l16+o)&15),
  //      tile t + ((l16+o)>>4), o = 15 - rs ----
  int gsrc[4];
  bool gcar[4];
  #pragma unroll
  for (int r = 0; r < 4; ++r) {
    int o = 15 - (quad * 4 + r);
    int s = l16 + o;
    gsrc[r] = (quad << 4) | (s & 15);
    gcar[r] = (s >= 16);
  }

  f32x4 oacc[4];
  #pragma unroll
  for (int t = 0; t < 4; ++t)
    #pragma unroll
    for (int j = 0; j < 4; ++j) oacc[t][j] = 0.f;
  float mrow[4] = {-INFINITY, -INFINITY, -INFINITY, -INFINITY};
  float lrow[4] = {0.f, 0.f, 0.f, 0.f};

  const int Blo0 = 31 - qt;  // rel-pos 64-col block at window bottom for kt=0

  for (int kt = 0; kt <= qt; ++kt) {
    const int j0 = kt * 64;
    __syncthreads();  // everyone done reading previous tiles

    // ---- DMA staging: K tile, V^T tile, new rel-pos panel (16B/lane, swizzled src) ----
    #pragma unroll
    for (int half = 0; half < 2; ++half) {
      const int ii = wave * 2 + half;
      const int j = ii * 64 + lane;
      {  // K: logical (key k, dim-chunk c8)
        const int k = j >> 3, c8 = (j & 7) ^ (k & 7);
        GLD16(Kbf + ((size_t)(b * SEQ + j0 + k)) * DKD + c8 * 8, Ks + ii * 512);
      }
      {  // V^T: logical (dim d, key-chunk c8)
        const int d = j >> 3, c8 = (j & 7) ^ (d & 7);
        GLD16(VTbf + ((size_t)(b * DKD + d)) * SEQ + j0 + c8 * 8, VsT + ii * 512);
      }
    }
    {
      const int Bg = Blo0 + kt + 1;  // new high panel (Bg == 32 -> zero rows)
      #pragma unroll
      for (int half = 0; half < 2; ++half) {
        const int ii = wave * 2 + half;
        const int j = ii * 64 + lane;
        const int c = j >> 3, c8 = (j & 7) ^ (c & 7);
        GLD16(PTbf + ((size_t)(Bg * 64 + c)) * DKD + c8 * 8,
              PsT + ((Bg & 1) << 12) + ii * 512);
      }
      if (kt == 0) {  // also stage the low panel once
        const int Bl = Blo0;
        #pragma unroll
        for (int half = 0; half < 2; ++half) {
          const int ii = wave * 2 + half;
          const int j = ii * 64 + lane;
          const int c = j >> 3, c8 = (j & 7) ^ (c & 7);
          GLD16(PTbf + ((size_t)(Bl * 64 + c)) * DKD + c8 * 8,
                PsT + ((Bl & 1) << 12) + ii * 512);
        }
      }
    }
    __syncthreads();  // DMA drained (vmcnt) + visible to all waves

    // ---- QK scores ----
    f32x4 sacc[4];
    #pragma unroll
    for (int t = 0; t < 4; ++t)
      #pragma unroll
      for (int j = 0; j < 4; ++j) sacc[t][j] = 0.f;
    #pragma unroll
    for (int ks = 0; ks < 2; ++ks)
      #pragma unroll
      for (int t = 0; t < 4; ++t) {
        bf16x8 bk = *(const bf16x8*)&Ks[CH(t * 16 + l16, ks * 4 + quad) << 3];
        sacc[t] = __builtin_amdgcn_mfma_f32_16x16x32_bf16(aq[ks], bk, sacc[t], 0, 0, 0);
      }

    // ---- bias MFMA: 5 column-tiles covering this wave's skew window ----
    f32x4 bacc[5];
    #pragma unroll
    for (int t = 0; t < 5; ++t)
      #pragma unroll
      for (int j = 0; j < 4; ++j) bacc[t][j] = 0.f;
    #pragma unroll
    for (int tt = 0; tt < 5; ++tt) {
      const int c = (tt + 3 - wave) * 16 + l16;          // slab col 0..127
      const int pan = (Blo0 + kt + (c >> 6)) & 1;
      const int pr = c & 63;
      #pragma unroll
      for (int ks = 0; ks < 2; ++ks) {
        bf16x8 bp = *(const bf16x8*)&PsT[(pan << 12) + (CH(pr, ks * 4 + quad) << 3)];
        bacc[tt] = __builtin_amdgcn_mfma_f32_16x16x32_bf16(aq[ks], bp, bacc[tt], 0, 0, 0);
      }
    }

    // ---- cross-lane skew gather (20 bpermutes) ----
    float g[5][4];
    #pragma unroll
    for (int tt = 0; tt < 5; ++tt)
      #pragma unroll
      for (int r = 0; r < 4; ++r) g[tt][r] = __shfl(bacc[tt][r], gsrc[r], 64);

    // ---- mask + online softmax (scores already scaled, exp2 domain) ----
    const bool diag = (kt == qt);
    float p[4][4];
    #pragma unroll
    for (int r = 0; r < 4; ++r) {
      const int rs = quad * 4 + r;
      float sv[4];
      #pragma unroll
      for (int t = 0; t < 4; ++t) {
        float sc = sacc[t][r] + (gcar[r] ? g[t + 1][r] : g[t][r]);
        if (diag && (t * 16 + l16 > wave * 16 + rs)) sc = -INFINITY;
        sv[t] = sc;
      }
      float rm = fmaxf(fmaxf(sv[0], sv[1]), fmaxf(sv[2], sv[3]));
      #pragma unroll
      for (int m = 1; m < 16; m <<= 1) rm = fmaxf(rm, __shfl_xor(rm, m, 16));
      float mn = fmaxf(mrow[r], rm);
      float alpha = exp2f(mrow[r] - mn);
      mrow[r] = mn;
      float ls = 0.f;
      #pragma unroll
      for (int t = 0; t < 4; ++t) {
        float e = exp2f(sv[t] - mn);
        p[t][r] = e;
        ls += e;
      }
      #pragma unroll
      for (int m = 1; m < 16; m <<= 1) ls += __shfl_xor(ls, m, 16);
      lrow[r] = lrow[r] * alpha + ls;
      #pragma unroll
      for (int dt = 0; dt < 4; ++dt) oacc[dt][r] *= alpha;
    }

    // ---- probs -> LDS (wave-private rows, swizzled), then PV MFMA ----
    #pragma unroll
    for (int t = 0; t < 4; ++t)
      #pragma unroll
      for (int r = 0; r < 4; ++r) {
        const int row = wave * 16 + quad * 4 + r;
        Pp[(CH(row, t * 2 + (l16 >> 3)) << 3) + (l16 & 7)] = f2bf(p[t][r]);
      }

    #pragma unroll
    for (int ks = 0; ks < 2; ++ks) {
      bf16x8 ap = *(const bf16x8*)&Pp[CH(wave * 16 + l16, ks * 4 + quad) << 3];
      #pragma unroll
      for (int dt = 0; dt < 4; ++dt) {
        bf16x8 bv = *(const bf16x8*)&VsT[CH(dt * 16 + l16, ks * 4 + quad) << 3];
        oacc[dt] = __builtin_amdgcn_mfma_f32_16x16x32_bf16(ap, bv, oacc[dt], 0, 0, 0);
      }
    }
  }

  // ---- epilogue ----
  float* Ob = O + ((size_t)(b * SEQ + r0)) * DKD;
  #pragma unroll
  for (int r = 0; r < 4; ++r) {
    float rl = 1.f / lrow[r];
    const int row = wave * 16 + quad * 4 + r;
    #pragma unroll
    for (int dt = 0; dt < 4; ++dt)
      Ob[(size_t)row * DKD + dt * 16 + l16] = oacc[dt][r] * rl;
  }
}

extern "C" void kernel_launch(void* const* d_in, const int* in_sizes, int n_in,
                              void* d_out, int out_size, void* d_ws, size_t ws_size,
                              hipStream_t stream) {
  const float* Q = (const float*)d_in[0];
  const float* K = (const float*)d_in[1];
  const float* V = (const float*)d_in[2];
  const float* P = (const float*)d_in[3];
  float* O = (float*)d_out;

  short* Kbf = (short*)d_ws;                              // 4,194,304 B
  short* VTbf = (short*)((char*)d_ws + 4194304);          // 4,194,304 B
  short* PTbf = (short*)((char*)d_ws + 8388608);          // 270,336 B

  hipLaunchKernelGGL(pre_convert, dim3(545), dim3(NTH), 0, stream, K, V, P, Kbf, VTbf, PTbf);
  hipLaunchKernelGGL(attn_mfma2, dim3(BSZ * (SEQ / 64)), dim3(NTH), 0, stream,
                     Q, Kbf, VTbf, PTbf, O);
}

// Round 4
// 140.344 us; speedup vs baseline: 3.9432x; 1.1684x over previous
//
#include <hip/hip_runtime.h>
#include <math.h>

#define BSZ 16
#define SEQ 2048
#define DKD 64
#define NTH 256

typedef __attribute__((ext_vector_type(8))) short bf16x8;
typedef __attribute__((ext_vector_type(8))) short short8;
typedef __attribute__((ext_vector_type(4))) float f32x4;

__device__ __forceinline__ short f2bf(float x) {
  union { float f; unsigned u; } c; c.f = x;
  unsigned r = c.u + 0x7fffu + ((c.u >> 16) & 1u);
  return (short)(r >> 16);
}

// async 16B/lane global->LDS DMA; ldst wave-uniform, lane i lands at ldst + i*16
#define GLD16(gsrc, ldst)                                                                  \
  __builtin_amdgcn_global_load_lds((const __attribute__((address_space(1))) void*)(gsrc), \
                                   (__attribute__((address_space(3))) void*)(ldst), 16, 0, 0)

// XOR chunk swizzle: logical (row, 16B-chunk c8) -> physical chunk index
#define CH(row, c8) (((row) << 3) + ((c8) ^ ((row) & 7)))

// ws layout: Kbf [16][2048][64] @ 0         (4,194,304 B)
//            VT  [16][64][2048] @ 4194304   (4,194,304 B)
//            PT  [2112][64]     @ 8388608   (270,336 B; rows 2048..2111 zero)
//            L   [16][2048] f32 @ 8658944   (131,072 B)   total 8,790,016 B

// ---------------- pre-kernel: bf16 convert K, transpose+convert V and P ----------------
__launch_bounds__(NTH)
__global__ void pre_convert(const float* __restrict__ K, const float* __restrict__ V,
                            const float* __restrict__ P, short* __restrict__ Kbf,
                            short* __restrict__ VTbf, short* __restrict__ PTbf) {
  __shared__ short T[64 * 65];
  const int blk = blockIdx.x;
  const int tid = threadIdx.x;
  if (blk < 1024) {
    // K convert (stream) + V transpose, 32-row chunk
    const int b = blk >> 6, ch = blk & 63;
    const float* Kb = K + ((size_t)(b * SEQ + ch * 32)) * DKD;
    const float* Vb = V + ((size_t)(b * SEQ + ch * 32)) * DKD;
    const int r = tid >> 3, c8 = (tid & 7) << 3;
    float4 a0 = *(const float4*)(Kb + r * DKD + c8);
    float4 a1 = *(const float4*)(Kb + r * DKD + c8 + 4);
    short8 ko;
    ko[0] = f2bf(a0.x); ko[1] = f2bf(a0.y); ko[2] = f2bf(a0.z); ko[3] = f2bf(a0.w);
    ko[4] = f2bf(a1.x); ko[5] = f2bf(a1.y); ko[6] = f2bf(a1.z); ko[7] = f2bf(a1.w);
    *(short8*)(Kbf + ((size_t)(b * SEQ + ch * 32 + r)) * DKD + c8) = ko;
    float4 v0 = *(const float4*)(Vb + r * DKD + c8);
    float4 v1 = *(const float4*)(Vb + r * DKD + c8 + 4);
    T[(c8 + 0) * 33 + r] = f2bf(v0.x); T[(c8 + 1) * 33 + r] = f2bf(v0.y);
    T[(c8 + 2) * 33 + r] = f2bf(v0.z); T[(c8 + 3) * 33 + r] = f2bf(v0.w);
    T[(c8 + 4) * 33 + r] = f2bf(v1.x); T[(c8 + 5) * 33 + r] = f2bf(v1.y);
    T[(c8 + 6) * 33 + r] = f2bf(v1.z); T[(c8 + 7) * 33 + r] = f2bf(v1.w);
    __syncthreads();
    const int d = tid >> 2, q8 = (tid & 3) << 3;
    short8 w;
    #pragma unroll
    for (int j = 0; j < 8; ++j) w[j] = T[d * 33 + q8 + j];
    *(short8*)(VTbf + ((size_t)(b * DKD + d)) * SEQ + ch * 32 + q8) = w;
  } else if (blk < 1056) {
    const int c0 = (blk - 1024) * 64;
    const int d = tid >> 2, cc4 = (tid & 3) << 4;
    #pragma unroll
    for (int j4 = 0; j4 < 4; ++j4) {
      const int c = cc4 + j4 * 4;
      float4 pv = *(const float4*)(P + (size_t)d * SEQ + c0 + c);
      T[(c + 0) * 65 + d] = f2bf(pv.x);
      T[(c + 1) * 65 + d] = f2bf(pv.y);
      T[(c + 2) * 65 + d] = f2bf(pv.z);
      T[(c + 3) * 65 + d] = f2bf(pv.w);
    }
    __syncthreads();
    const int c = tid >> 2, d4 = (tid & 3) << 4;
    short8 w0, w1;
    #pragma unroll
    for (int j = 0; j < 8; ++j) { w0[j] = T[c * 65 + d4 + j]; w1[j] = T[c * 65 + d4 + 8 + j]; }
    short* Po = PTbf + ((size_t)(c0 + c)) * DKD + d4;
    *(short8*)(Po + 0) = w0;
    *(short8*)(Po + 8) = w1;
  } else {
    short8 z = {0, 0, 0, 0, 0, 0, 0, 0};
    short* Po = PTbf + (size_t)SEQ * DKD + tid * 16;
    *(short8*)(Po + 0) = z;
    *(short8*)(Po + 8) = z;
  }
}

// ---------------- main attention kernel (key-range split, fixed-max softmax) ----------------
__launch_bounds__(NTH, 4)
__global__ void attn_split(const float* __restrict__ Q,
                           const short* __restrict__ Kbf,
                           const short* __restrict__ VTbf,
                           const short* __restrict__ PTbf,
                           float* __restrict__ Oacc,
                           float* __restrict__ Lacc) {
  // 40 KB total -> exactly 4 blocks/CU (160 KB LDS)
  __shared__ __align__(16) short Ks[64 * 64];       // K tile  [key][dim]
  __shared__ __align__(16) short VsT[64 * 64];      // V^T     [dim][key]
  __shared__ __align__(16) short PsT[2 * 64 * 64];  // relpos  [2 panels][col][dim]
  __shared__ __align__(16) short Pp[64 * 64];       // probs   [row][key] (wave-private rows)

  const int tid = threadIdx.x;
  const int lane = tid & 63;
  const int wave = tid >> 6;
  const int l16 = lane & 15;
  const int quad = lane >> 4;

  // block decode: 1024 blocks = 32 qt-slots x (16 batches x 2 halves), balanced per CU
  const int i = blockIdx.x;
  const int qidx = i >> 5;
  const int s = i & 31;
  const int b = s & 15;
  const int h = s >> 4;
  const int qt = (qidx < 16) ? (31 - qidx) : (qidx - 16);
  const int r0 = qt * 64;
  const int m = (qt + 2) >> 1;            // ceil((qt+1)/2)
  const int kt0 = h ? m : 0;
  const int kt1 = h ? (qt + 1) : m;       // [kt0, kt1)
  const float SC = 0.125f * 1.4426950408889634f;  // (1/sqrt(dk)) * log2(e), folded into Q

  // ---- persistent pre-scaled Q A-fragments ----
  bf16x8 aq[2];
  {
    const float* Qr = Q + ((size_t)(b * SEQ + r0 + wave * 16 + l16)) * DKD + quad * 8;
    #pragma unroll
    for (int ks = 0; ks < 2; ++ks) {
      float4 x = *(const float4*)(Qr + ks * 32);
      float4 y = *(const float4*)(Qr + ks * 32 + 4);
      bf16x8 t;
      t[0] = f2bf(x.x * SC); t[1] = f2bf(x.y * SC); t[2] = f2bf(x.z * SC); t[3] = f2bf(x.w * SC);
      t[4] = f2bf(y.x * SC); t[5] = f2bf(y.y * SC); t[6] = f2bf(y.z * SC); t[7] = f2bf(y.w * SC);
      aq[ks] = t;
    }
  }

  // skew-gather lane tables
  int gsrc[4];
  bool gcar[4];
  #pragma unroll
  for (int r = 0; r < 4; ++r) {
    int o = 15 - (quad * 4 + r);
    int ssrc = l16 + o;
    gsrc[r] = (quad << 4) | (ssrc & 15);
    gcar[r] = (ssrc >= 16);
  }

  bf16x8 ONES;
  #pragma unroll
  for (int j = 0; j < 8; ++j) ONES[j] = (short)0x3F80;

  f32x4 oacc[4];
  #pragma unroll
  for (int t = 0; t < 4; ++t)
    #pragma unroll
    for (int j = 0; j < 4; ++j) oacc[t][j] = 0.f;
  f32x4 bl;
  #pragma unroll
  for (int j = 0; j < 4; ++j) bl[j] = 0.f;

  const int Blo0 = 31 - qt;

  for (int kt = kt0; kt < kt1; ++kt) {
    const int j0 = kt * 64;
    __syncthreads();  // everyone done reading previous tiles

    // ---- DMA staging ----
    #pragma unroll
    for (int half = 0; half < 2; ++half) {
      const int ii = wave * 2 + half;
      const int j = ii * 64 + lane;
      {  // K
        const int k = j >> 3, c8 = (j & 7) ^ (k & 7);
        GLD16(Kbf + ((size_t)(b * SEQ + j0 + k)) * DKD + c8 * 8, Ks + ii * 512);
      }
      {  // V^T
        const int d = j >> 3, c8 = (j & 7) ^ (d & 7);
        GLD16(VTbf + ((size_t)(b * DKD + d)) * SEQ + j0 + c8 * 8, VsT + ii * 512);
      }
    }
    {
      const int Bg = Blo0 + kt + 1;  // new high panel (Bg == 32 -> zero rows)
      #pragma unroll
      for (int half = 0; half < 2; ++half) {
        const int ii = wave * 2 + half;
        const int j = ii * 64 + lane;
        const int c = j >> 3, c8 = (j & 7) ^ (c & 7);
        GLD16(PTbf + ((size_t)(Bg * 64 + c)) * DKD + c8 * 8,
              PsT + ((Bg & 1) << 12) + ii * 512);
      }
      if (kt == kt0) {  // stage the low panel once per block
        const int Bl = Blo0 + kt0;
        #pragma unroll
        for (int half = 0; half < 2; ++half) {
          const int ii = wave * 2 + half;
          const int j = ii * 64 + lane;
          const int c = j >> 3, c8 = (j & 7) ^ (c & 7);
          GLD16(PTbf + ((size_t)(Bl * 64 + c)) * DKD + c8 * 8,
                PsT + ((Bl & 1) << 12) + ii * 512);
        }
      }
    }
    __syncthreads();  // DMA drained + visible

    // ---- QK scores ----
    f32x4 sacc[4];
    #pragma unroll
    for (int t = 0; t < 4; ++t)
      #pragma unroll
      for (int j = 0; j < 4; ++j) sacc[t][j] = 0.f;
    #pragma unroll
    for (int ks = 0; ks < 2; ++ks)
      #pragma unroll
      for (int t = 0; t < 4; ++t) {
        bf16x8 bk = *(const bf16x8*)&Ks[CH(t * 16 + l16, ks * 4 + quad) << 3];
        sacc[t] = __builtin_amdgcn_mfma_f32_16x16x32_bf16(aq[ks], bk, sacc[t], 0, 0, 0);
      }

    // ---- bias MFMA: 5 column-tiles for this wave's skew window ----
    f32x4 bacc[5];
    #pragma unroll
    for (int t = 0; t < 5; ++t)
      #pragma unroll
      for (int j = 0; j < 4; ++j) bacc[t][j] = 0.f;
    #pragma unroll
    for (int tt = 0; tt < 5; ++tt) {
      const int c = (tt + 3 - wave) * 16 + l16;
      const int pan = (Blo0 + kt + (c >> 6)) & 1;
      const int pr = c & 63;
      #pragma unroll
      for (int ks = 0; ks < 2; ++ks) {
        bf16x8 bp = *(const bf16x8*)&PsT[(pan << 12) + (CH(pr, ks * 4 + quad) << 3)];
        bacc[tt] = __builtin_amdgcn_mfma_f32_16x16x32_bf16(aq[ks], bp, bacc[tt], 0, 0, 0);
      }
    }

    // ---- cross-lane skew gather ----
    float g[5][4];
    #pragma unroll
    for (int tt = 0; tt < 5; ++tt)
      #pragma unroll
      for (int r = 0; r < 4; ++r) g[tt][r] = __shfl(bacc[tt][r], gsrc[r], 64);

    // ---- mask + fixed-max softmax numerator; write probs ----
    const bool diag = (kt == qt);
    #pragma unroll
    for (int r = 0; r < 4; ++r) {
      const int rs = quad * 4 + r;
      #pragma unroll
      for (int t = 0; t < 4; ++t) {
        float sc = sacc[t][r] + (gcar[r] ? g[t + 1][r] : g[t][r]);
        if (diag && (t * 16 + l16 > wave * 16 + rs)) sc = -INFINITY;
        float e = exp2f(sc);
        const int row = wave * 16 + rs;
        Pp[(CH(row, t * 2 + (l16 >> 3)) << 3) + (l16 & 7)] = f2bf(e);
      }
    }

    // ---- PV MFMA + free row-sum via ones-B ----
    #pragma unroll
    for (int ks = 0; ks < 2; ++ks) {
      bf16x8 ap = *(const bf16x8*)&Pp[CH(wave * 16 + l16, ks * 4 + quad) << 3];
      #pragma unroll
      for (int dt = 0; dt < 4; ++dt) {
        bf16x8 bv = *(const bf16x8*)&VsT[CH(dt * 16 + l16, ks * 4 + quad) << 3];
        oacc[dt] = __builtin_amdgcn_mfma_f32_16x16x32_bf16(ap, bv, oacc[dt], 0, 0, 0);
      }
      bl = __builtin_amdgcn_mfma_f32_16x16x32_bf16(ap, ONES, bl, 0, 0, 0);
    }
  }

  // ---- epilogue: atomic-accumulate unnormalized O and row sums ----
  if (kt1 > kt0) {
    float* Ob = Oacc + ((size_t)(b * SEQ + r0)) * DKD;
    #pragma unroll
    for (int r = 0; r < 4; ++r) {
      const int row = wave * 16 + quad * 4 + r;
      #pragma unroll
      for (int dt = 0; dt < 4; ++dt)
        unsafeAtomicAdd(&Ob[(size_t)row * DKD + dt * 16 + l16], oacc[dt][r]);
    }
    if (l16 == 0) {
      #pragma unroll
      for (int r = 0; r < 4; ++r)
        unsafeAtomicAdd(&Lacc[b * SEQ + r0 + wave * 16 + quad * 4 + r], bl[r]);
    }
  }
}

// ---------------- normalize: O /= L ----------------
__launch_bounds__(NTH)
__global__ void norm_out(float* __restrict__ O, const float* __restrict__ L) {
  const int tid = threadIdx.x;
  const int row = blockIdx.x * 16 + (tid >> 4);
  const int c4 = (tid & 15) << 2;
  const float rl = 1.0f / L[row];
  float4* p = (float4*)(O + (size_t)row * DKD + c4);
  float4 v = *p;
  v.x *= rl; v.y *= rl; v.z *= rl; v.w *= rl;
  *p = v;
}

extern "C" void kernel_launch(void* const* d_in, const int* in_sizes, int n_in,
                              void* d_out, int out_size, void* d_ws, size_t ws_size,
                              hipStream_t stream) {
  const float* Q = (const float*)d_in[0];
  const float* K = (const float*)d_in[1];
  const float* V = (const float*)d_in[2];
  const float* P = (const float*)d_in[3];
  float* O = (float*)d_out;

  short* Kbf = (short*)d_ws;                          // 4,194,304 B
  short* VTbf = (short*)((char*)d_ws + 4194304);      // 4,194,304 B
  short* PTbf = (short*)((char*)d_ws + 8388608);      // 270,336 B
  float* Lacc = (float*)((char*)d_ws + 8658944);      // 131,072 B

  hipMemsetAsync(O, 0, (size_t)BSZ * SEQ * DKD * sizeof(float), stream);
  hipMemsetAsync(Lacc, 0, (size_t)BSZ * SEQ * sizeof(float), stream);
  hipLaunchKernelGGL(pre_convert, dim3(1057), dim3(NTH), 0, stream, K, V, P, Kbf, VTbf, PTbf);
  hipLaunchKernelGGL(attn_split, dim3(1024), dim3(NTH), 0, stream, Q, Kbf, VTbf, PTbf, O, Lacc);
  hipLaunchKernelGGL(norm_out, dim3(BSZ * SEQ / 16), dim3(NTH), 0, stream, O, Lacc);
}